// Round 9
// baseline (96.867 us; speedup 1.0000x reference)
//
#include <hip/hip_runtime.h>

typedef __attribute__((ext_vector_type(4))) float f32x4;
typedef __attribute__((ext_vector_type(8))) short bf16x8;

#define S_LEN 4096

__device__ inline short f2bf(float f) {
    union { float f; unsigned u; } v; v.f = f;
    unsigned r = (v.u + 0x7fffu + ((v.u >> 16) & 1u)) >> 16;
    return (short)r;
}
__device__ inline unsigned pack2bf(float a, float b) {
    return (unsigned)(unsigned short)f2bf(a) | ((unsigned)(unsigned short)f2bf(b) << 16);
}
__device__ inline unsigned cvt_pk_bf16(float lo, float hi) {
    unsigned r;
    asm("v_cvt_pk_bf16_f32 %0, %1, %2" : "=v"(r) : "v"(lo), "v"(hi));
    return r;
}
__device__ inline void gload_lds16(const void* g, void* l) {
    __builtin_amdgcn_global_load_lds(
        (const __attribute__((address_space(1))) unsigned int*)g,
        (__attribute__((address_space(3))) unsigned int*)l, 16, 0, 0);
}

// Wsz per-K-step layout: Wsz[t*6144 + g*32 + kk] = bf16(W_m[k=t*32+kk][c]),
// g = m*64 + c. A K-step's B tile [192][32] is 12 KB, staged linearly to LDS.
__global__ __launch_bounds__(256) void wconv_kernel(const float* __restrict__ Wq,
        const float* __restrict__ Wk, const float* __restrict__ Wv,
        short* __restrict__ Wsz) {
    int idx = blockIdx.x * 256 + threadIdx.x;          // 0..196607
    int t = idx / 6144;
    int rem = idx - t * 6144;
    int g = rem >> 5, kk = rem & 31;
    int k = t * 32 + kk;
    int m = g >> 6, c = g & 63;
    const float* W = (m == 0) ? Wq : (m == 1) ? Wk : Wv;
    Wsz[idx] = f2bf(W[k * 64 + c]);
}

// BM=32 x BN=192, BK=32. 4 waves: (wr 0..1 rows, wc 0..1 cols of 96).
// B via LDS double-buffer (2x12KB); A direct global->reg (+cvt_pk);
// one __syncthreads per K-step; 2 blocks/CU hide the barrier drains.
__global__ __launch_bounds__(256, 4) void qkv_kernel(const float* __restrict__ x,
        const short* __restrict__ Wsz, short* __restrict__ Qb,
        short* __restrict__ Kb, short* __restrict__ Vt) {
    __shared__ __align__(16) char Bl[2][12288];        // 24 KB
    const int tid = threadIdx.x;
    const int wv = tid >> 6, lane = tid & 63;
    const int wr = wv & 1, wc = wv >> 1;
    const int lr = lane & 15, lg = lane >> 4;
    const int rowbase = blockIdx.x * 32 + wr * 16;

    f32x4 acc[6];
#pragma unroll
    for (int i = 0; i < 6; i++) acc[i] = {0.f, 0.f, 0.f, 0.f};

    const float* xrow = x + (size_t)(rowbase + lr) * 1024 + lg * 8;
    const char* wsrc = (const char*)Wsz + tid * 16;

#define STAGEB(t_, buf_)                                                    \
    {                                                                       \
        const char* s_ = wsrc + (t_) * 12288;                               \
        char* d_ = &Bl[(buf_)][tid * 16];                                   \
        gload_lds16(s_,        d_);                                         \
        gload_lds16(s_ + 4096, d_ + 4096);                                  \
        gload_lds16(s_ + 8192, d_ + 8192);                                  \
    }

    STAGEB(0, 0);
    __syncthreads();

#pragma unroll 4
    for (int t = 0; t < 32; t++) {
        if (t + 1 < 32) STAGEB(t + 1, (t + 1) & 1);

        // A frag: k = t*32 + lg*8 + j, row = rowbase + lr
        f32x4 a0 = *(const f32x4*)(xrow + t * 32);
        f32x4 a1 = *(const f32x4*)(xrow + t * 32 + 4);
        union { unsigned u[4]; bf16x8 v; } au;
        au.u[0] = cvt_pk_bf16(a0[0], a0[1]);
        au.u[1] = cvt_pk_bf16(a0[2], a0[3]);
        au.u[2] = cvt_pk_bf16(a1[0], a1[1]);
        au.u[3] = cvt_pk_bf16(a1[2], a1[3]);

        const char* Bb = &Bl[t & 1][0];
#pragma unroll
        for (int cf = 0; cf < 6; cf++) {
            int brow = wc * 96 + cf * 16 + lr;
            bf16x8 b = *(const bf16x8*)(Bb + brow * 64 + lg * 16);
            acc[cf] = __builtin_amdgcn_mfma_f32_16x16x32_bf16(au.v, b, acc[cf], 0, 0, 0);
        }
        __syncthreads();
    }
#undef STAGEB

#pragma unroll
    for (int cf = 0; cf < 6; cf++) {
        int gcol = wc * 96 + cf * 16 + lr;
        int m = gcol >> 6, cm = gcol & 63;
#pragma unroll
        for (int r = 0; r < 4; r++) {
            int row = rowbase + lg * 4 + r;
            short bv = f2bf(acc[cf][r]);
            if (m == 0)      Qb[(size_t)row * 64 + cm] = bv;
            else if (m == 1) Kb[(size_t)row * 64 + cm] = bv;
            else {
                int b = row >> 12, ss = row & 4095;
                Vt[(size_t)(b * 64 + cm) * S_LEN + ss] = bv;
            }
        }
    }
}

// 1 wave/block. Swapped-operand attention: S^T = mfma(K,Q), O^T = mfma(Vt, P).
__global__ __launch_bounds__(64) void attn_partial_kernel(const short* __restrict__ Qb,
        const short* __restrict__ Kb, const short* __restrict__ Vt,
        float* __restrict__ o_part, float* __restrict__ m_part, float* __restrict__ l_part,
        int G, int NPB, int C) {
    __shared__ __align__(16) char Plds[32 * 64 * 2];
    const int lane = threadIdx.x;
    const int lr = lane & 15, lg = lane >> 4;
    const int j = blockIdx.x;
    const int bb = j / NPB;
    int jb = j - bb * NPB;
    int g = 0, base = 0;
    while (jb >= base + G * (g + 1)) { base += G * (g + 1); g++; }
    int u = jb - base;
    int qdiv = u / (g + 1);
    const int qi = g * G + qdiv;
    const int cch = u - qdiv * (g + 1);
    const int qb = qi * 32;
    const int kv_start = cch * C;
    const int kv_end = min(qb + 32, kv_start + C);

    bf16x8 qa[2][2];
#pragma unroll
    for (int qf = 0; qf < 2; qf++)
#pragma unroll
        for (int dk = 0; dk < 2; dk++)
            qa[qf][dk] = *(const bf16x8*)(Qb + (size_t)(bb * S_LEN + qb + qf * 16 + lr) * 64 + dk * 32 + lg * 8);

    f32x4 o[2][4];
    float mrun[2] = {-1e30f, -1e30f}, lrun[2] = {0.f, 0.f};
#pragma unroll
    for (int qf = 0; qf < 2; qf++)
#pragma unroll
        for (int df = 0; df < 4; df++) o[qf][df] = {0.f, 0.f, 0.f, 0.f};

    const int kvb0 = kv_start >> 6, kvb1 = (kv_end + 63) >> 6;
    for (int kvb = kvb0; kvb < kvb1; kvb++) {
        const int kv0 = kvb << 6;

        bf16x8 kb[4][2], vb[2][4];
#pragma unroll
        for (int kf = 0; kf < 4; kf++)
#pragma unroll
            for (int dk = 0; dk < 2; dk++)
                kb[kf][dk] = *(const bf16x8*)(Kb + (size_t)(bb * S_LEN + kv0 + kf * 16 + lr) * 64 + dk * 32 + lg * 8);
#pragma unroll
        for (int kk = 0; kk < 2; kk++)
#pragma unroll
            for (int df = 0; df < 4; df++)
                vb[kk][df] = *(const bf16x8*)(Vt + (size_t)(bb * 64 + df * 16 + lr) * S_LEN + kv0 + kk * 32 + lg * 8);

        f32x4 s[2][4];
#pragma unroll
        for (int qf = 0; qf < 2; qf++)
#pragma unroll
            for (int kf = 0; kf < 4; kf++) {
                f32x4 z = {0.f, 0.f, 0.f, 0.f};
                z = __builtin_amdgcn_mfma_f32_16x16x32_bf16(kb[kf][0], qa[qf][0], z, 0, 0, 0);
                s[qf][kf] = __builtin_amdgcn_mfma_f32_16x16x32_bf16(kb[kf][1], qa[qf][1], z, 0, 0, 0);
            }

        const bool needmask = (kv0 + 63) > qb;
#pragma unroll
        for (int qf = 0; qf < 2; qf++)
#pragma unroll
            for (int kf = 0; kf < 4; kf++)
#pragma unroll
                for (int r = 0; r < 4; r++) {
                    float v = s[qf][kf][r] * 0.125f;
                    if (needmask) {
                        int row = qb + qf * 16 + lr;
                        int col = kv0 + kf * 16 + lg * 4 + r;
                        if (col > row) v = -1e30f;
                    }
                    s[qf][kf][r] = v;
                }

#pragma unroll
        for (int qf = 0; qf < 2; qf++) {
            float pm = -1e30f;
#pragma unroll
            for (int kf = 0; kf < 4; kf++)
#pragma unroll
                for (int r = 0; r < 4; r++) pm = fmaxf(pm, s[qf][kf][r]);
            pm = fmaxf(pm, __shfl_xor(pm, 16, 64));
            pm = fmaxf(pm, __shfl_xor(pm, 32, 64));
            float mnew = fmaxf(mrun[qf], pm);
            float fac = __expf(mrun[qf] - mnew);
            mrun[qf] = mnew;

            const int q = qf * 16 + lr;
            const int swz = (q & 7) << 4;
            float rs = 0.f;
#pragma unroll
            for (int kf = 0; kf < 4; kf++) {
                float p0 = __expf(s[qf][kf][0] - mnew);
                float p1 = __expf(s[qf][kf][1] - mnew);
                float p2 = __expf(s[qf][kf][2] - mnew);
                float p3 = __expf(s[qf][kf][3] - mnew);
                rs += (p0 + p1) + (p2 + p3);
                uint2 w; w.x = pack2bf(p0, p1); w.y = pack2bf(p2, p3);
                int byt = (q * 128 + kf * 32 + lg * 8) ^ swz;
                *(uint2*)(Plds + byt) = w;
            }
            rs += __shfl_xor(rs, 16, 64);
            rs += __shfl_xor(rs, 32, 64);
            lrun[qf] = lrun[qf] * fac + rs;
#pragma unroll
            for (int df = 0; df < 4; df++)
#pragma unroll
                for (int r = 0; r < 4; r++) o[qf][df][r] *= fac;
        }

        bf16x8 pa[2][2];
#pragma unroll
        for (int qf = 0; qf < 2; qf++)
#pragma unroll
            for (int kk = 0; kk < 2; kk++) {
                int q = qf * 16 + lr;
                int byt = (q * 128 + kk * 64 + lg * 16) ^ ((q & 7) << 4);
                pa[qf][kk] = *(const bf16x8*)(Plds + byt);
            }

#pragma unroll
        for (int qf = 0; qf < 2; qf++)
#pragma unroll
            for (int df = 0; df < 4; df++) {
                o[qf][df] = __builtin_amdgcn_mfma_f32_16x16x32_bf16(vb[0][df], pa[qf][0], o[qf][df], 0, 0, 0);
                o[qf][df] = __builtin_amdgcn_mfma_f32_16x16x32_bf16(vb[1][df], pa[qf][1], o[qf][df], 0, 0, 0);
            }
    }

#pragma unroll
    for (int qf = 0; qf < 2; qf++)
#pragma unroll
        for (int df = 0; df < 4; df++)
            *(f32x4*)(o_part + ((size_t)j * 32 + qf * 16 + lr) * 64 + df * 16 + lg * 4) = o[qf][df];
    if (lg == 0) {
#pragma unroll
        for (int qf = 0; qf < 2; qf++) {
            m_part[(size_t)j * 32 + qf * 16 + lr] = mrun[qf];
            l_part[(size_t)j * 32 + qf * 16 + lr] = lrun[qf];
        }
    }
}

// One thread per output element; m/l loads are wave-uniform, o loads coalesced.
__global__ __launch_bounds__(256) void combine_kernel(const float* __restrict__ o_part,
        const float* __restrict__ m_part, const float* __restrict__ l_part,
        float* __restrict__ out, int G, int NPB) {
    const int idx = blockIdx.x * 256 + threadIdx.x;
    const int col = idx & 63;
    const int rowg = idx >> 6;
    const int bb = rowg >> 12;
    const int srow = rowg & 4095;
    const int qi = srow >> 5;
    const int r = srow & 31;
    const int g = qi / G;
    const int n = g + 1;
    const int jb0 = bb * NPB + G * g * (g + 1) / 2 + (qi - g * G) * n;

    float M = -1e30f;
    for (int c = 0; c < n; c++) M = fmaxf(M, m_part[(size_t)(jb0 + c) * 32 + r]);
    float L = 0.f, acc = 0.f;
    for (int c = 0; c < n; c++) {
        float w = __expf(m_part[(size_t)(jb0 + c) * 32 + r] - M);
        L += l_part[(size_t)(jb0 + c) * 32 + r] * w;
        acc += o_part[((size_t)(jb0 + c) * 32 + r) * 64 + col] * w;
    }
    out[idx] = acc / L;
}

extern "C" void kernel_launch(void* const* d_in, const int* in_sizes, int n_in,
                              void* d_out, int out_size, void* d_ws, size_t ws_size,
                              hipStream_t stream) {
    const float* x  = (const float*)d_in[0];
    const float* Wq = (const float*)d_in[1];
    const float* Wk = (const float*)d_in[2];
    const float* Wv = (const float*)d_in[3];
    float* out = (float*)d_out;

    char* ws = (char*)d_ws;
    short* Wsz = (short*)(ws);                  // 384 KB (per-K-step layout)
    short* Qb = (short*)(ws + 0x60000);         // 2 MB
    short* Kb = (short*)(ws + 0x260000);        // 2 MB
    short* Vt = (short*)(ws + 0x460000);        // 2 MB

    // chunk tiers: C=256 (G=8, NPB=1088) -> C=512 -> C=1024, by workspace.
    int G = 8, NPB = 1088, C = 256;
    {
        size_t need = 0x660000 + (size_t)4 * NPB * 32 * 66 * 4;
        if (need > ws_size) { G = 16; NPB = 576; C = 512; }
        need = 0x660000 + (size_t)4 * NPB * 32 * 66 * 4;
        if (need > ws_size) { G = 32; NPB = 320; C = 1024; }
    }
    const int njobs = 4 * NPB;
    float* o_part = (float*)(ws + 0x660000);
    float* m_part = o_part + (size_t)njobs * 32 * 64;
    float* l_part = m_part + (size_t)njobs * 32;

    hipLaunchKernelGGL(wconv_kernel, dim3(768), dim3(256), 0, stream, Wq, Wk, Wv, Wsz);
    hipLaunchKernelGGL(qkv_kernel,  dim3(512), dim3(256), 0, stream, x, Wsz, Qb, Kb, Vt);
    hipLaunchKernelGGL(attn_partial_kernel, dim3(njobs), dim3(64), 0, stream,
                       Qb, Kb, Vt, o_part, m_part, l_part, G, NPB, C);
    hipLaunchKernelGGL(combine_kernel, dim3(4096), dim3(256), 0, stream,
                       o_part, m_part, l_part, out, G, NPB);
}